// Round 4
// baseline (10426.731 us; speedup 1.0000x reference)
//
#include <hip/hip_runtime.h>
#include <hip/hip_bf16.h>

// ---------------------------------------------------------------------------
// PointerLSTM: B=64, L=1024, D=256, H=256, T=1024 steps.
//   tanh(x) = 1 - 2/(1 + e^{2x});  e^{2(a+d)} = A*D with A=e^{2a}, D=e^{2d}
//   score_l = const - 2*sum_h V_h/(1+A_lh*D_th)   -> const cancels in softmax
// Recurrence kept FULL F32 (cheap); A and hseq are bf16 (error ~1e-5, far
// under the 1.29e-4 threshold).
// R3 bugfix: k3b even-h extraction was bfbits2f(hp.x<<16) == 0 (double shift)
// -> w2d missed all even-h terms -> the 5.04e-4 error seen in R1 AND R3.
// ---------------------------------------------------------------------------

#define LOG2E  1.4426950408889634f
#define C2LOG2E 2.8853900817779268f   // 2*log2(e)

typedef float f32x2 __attribute__((ext_vector_type(2)));

__device__ __forceinline__ unsigned f2bf(float f) {
  unsigned u = __builtin_bit_cast(unsigned, f);
  return (u + 0x7fffu + ((u >> 16) & 1u)) >> 16;   // round-to-nearest-even
}
// bf16 bits in the LOW half of `bits` -> float. (High half ignored.)
__device__ __forceinline__ float bfbits2f(unsigned bits) {
  return __builtin_bit_cast(float, bits << 16);
}

#if defined(__has_builtin) && __has_builtin(__builtin_amdgcn_rcpf)
#  define FAST_RCP(x) __builtin_amdgcn_rcpf(x)
#else
#  define FAST_RCP(x) (1.0f / (x))
#endif

// --- k0: pack Wr (256x1024 f32) into f32 k-pairs:
//     Wrp2[(m*1024+j)*2 + p] = Wr[2m+p][j]   (m=0..127, j=0..1023, p=0..1)
__global__ __launch_bounds__(256) void k0_pack(const float* __restrict__ Wr,
                                               float* __restrict__ Wrp2) {
  int idx = blockIdx.x * 256 + threadIdx.x;
  if (idx >= 128 * 1024) return;
  int m = idx >> 10, j = idx & 1023;
  float2 v;
  v.x = Wr[(2 * m) * 1024 + j];
  v.y = Wr[(2 * m + 1) * 1024 + j];
  ((float2*)Wrp2)[idx] = v;
}

// --- k1: w1e = x@W1 + b1 ; store AT[b][h][l] = bf16(exp2(C2*w1e))   (transposed!)
__global__ __launch_bounds__(256) void k1_w1e(const float* __restrict__ x,
                                              const float* __restrict__ W1,
                                              const float* __restrict__ b1,
                                              unsigned short* __restrict__ AT) {
  const int b  = blockIdx.x >> 6;
  const int lb = blockIdx.x & 63;   // 16 l-rows per block
  const int h  = threadIdx.x;
  float acc[16];
  const float bias = b1[h];
#pragma unroll
  for (int r = 0; r < 16; ++r) acc[r] = bias;
  const float* xb = x + ((size_t)(b * 1024 + lb * 16)) * 256;
  for (int d0 = 0; d0 < 256; d0 += 4) {
    const float w0 = W1[(d0 + 0) * 256 + h];
    const float w1 = W1[(d0 + 1) * 256 + h];
    const float w2 = W1[(d0 + 2) * 256 + h];
    const float w3 = W1[(d0 + 3) * 256 + h];
#pragma unroll
    for (int r = 0; r < 16; ++r) {
      const float4 xv = *(const float4*)(xb + r * 256 + d0);
      acc[r] = fmaf(xv.x, w0, acc[r]);
      acc[r] = fmaf(xv.y, w1, acc[r]);
      acc[r] = fmaf(xv.z, w2, acc[r]);
      acc[r] = fmaf(xv.w, w3, acc[r]);
    }
  }
  unsigned short* outp = AT + ((size_t)(b * 256 + h)) * 1024 + lb * 16;
#pragma unroll
  for (int r = 0; r < 16; r += 2) {
    unsigned u0 = f2bf(exp2f(C2LOG2E * acc[r]));
    unsigned u1 = f2bf(exp2f(C2LOG2E * acc[r + 1]));
    *(unsigned*)(outp + r) = u0 | (u1 << 16);
  }
}

// --- k2: xz[b][j] = x[b][1023][:] @ Wk[:,j] + b[j]
__global__ __launch_bounds__(256) void k2_xz(const float* __restrict__ x,
                                             const float* __restrict__ Wk,
                                             const float* __restrict__ bvec,
                                             float* __restrict__ xz) {
  const int b = blockIdx.x, tid = threadIdx.x;
  float acc[4] = {bvec[tid], bvec[256 + tid], bvec[512 + tid], bvec[768 + tid]};
  const float* xr = x + ((size_t)b * 1024 + 1023) * 256;
  for (int d0 = 0; d0 < 256; d0 += 4) {
    const float4 xv = *(const float4*)(xr + d0);
#pragma unroll
    for (int i = 0; i < 4; ++i) {
      const float xs = (i == 0) ? xv.x : (i == 1) ? xv.y : (i == 2) ? xv.z : xv.w;
#pragma unroll
      for (int q = 0; q < 4; ++q)
        acc[q] = fmaf(xs, Wk[(size_t)(d0 + i) * 1024 + q * 256 + tid], acc[q]);
    }
  }
#pragma unroll
  for (int q = 0; q < 4; ++q) xz[b * 1024 + q * 256 + tid] = acc[q];
}

// --- k3: sequential LSTM recurrence, FULL F32. One WG per batch b.
// 512 threads: phase 1, thread computes z-columns (2*tid, 2*tid+1) via f32
// pair-packed Wr. Phase 2: threads 0..255 do gates (one h-elem each) with
// precise expf/tanhf; h kept f32 in LDS; hseq stored bf16.
__global__ __launch_bounds__(512) void k3_recur(const float* __restrict__ xz,
                                                const float* __restrict__ Wrp2,
                                                unsigned short* __restrict__ hseq) {
  __shared__ float z_lds[1024];
  __shared__ __align__(16) float h_lds[256];
  const int b = blockIdx.x;
  const int tid = threadIdx.x;
  const int j0 = tid * 2;
  float c = 0.f;
  if (tid < 256) h_lds[tid] = 0.f;
  const float za0 = xz[b * 1024 + j0];
  const float za1 = xz[b * 1024 + j0 + 1];
  const float4* W4 = (const float4*)Wrp2;   // W4[q*1024 + tid]     : k-pair 4q,4q+1,  cols j0,j0+1
                                            // W4[q*1024 + 512+tid] : k-pair 4q+2,4q+3, cols j0,j0+1
  __syncthreads();
  for (int t = 0; t < 1024; ++t) {
    // phase 1: z = xz + h @ Wr (f32, packed pairs)
    f32x2 acc0 = {za0, 0.f};
    f32x2 acc1 = {za1, 0.f};
#pragma unroll 4
    for (int q = 0; q < 64; ++q) {
      const float4 hq = *(const float4*)&h_lds[4 * q];     // LDS broadcast
      const float4 w0 = W4[(size_t)q * 1024 + tid];
      const float4 w1 = W4[(size_t)q * 1024 + 512 + tid];
      const f32x2 h01 = {hq.x, hq.y};
      const f32x2 h23 = {hq.z, hq.w};
      acc0 += h01 * (f32x2){w0.x, w0.y};
      acc1 += h01 * (f32x2){w0.z, w0.w};
      acc0 += h23 * (f32x2){w1.x, w1.y};
      acc1 += h23 * (f32x2){w1.z, w1.w};
    }
    z_lds[j0]     = acc0.x + acc0.y;
    z_lds[j0 + 1] = acc1.x + acc1.y;
    __syncthreads();
    // phase 2: gates + state update (threads 0..255, one h-elem each)
    if (tid < 256) {
      const float zi = z_lds[tid];
      const float zf = z_lds[tid + 256];
      const float zg = z_lds[tid + 512];
      const float zo = z_lds[tid + 768];
      const float ig = 1.f / (1.f + expf(-zi));
      const float fg = 1.f / (1.f + expf(-zf));
      const float gg = tanhf(zg);
      const float og = 1.f / (1.f + expf(-zo));
      c = fmaf(fg, c, ig * gg);
      const float h = og * tanhf(c);
      h_lds[tid] = h;
      hseq[(size_t)(t * 64 + b) * 256 + tid] = (unsigned short)f2bf(h);
    }
    __syncthreads();
  }
}

// --- k3b: w2d = hseq @ W2 + b2 for all (t,b); store D[b][t][h] = f32(exp2(C2*w2d))
// hseq dword m = (h[2m] in LOW half, h[2m+1] in HIGH half), row = t*64+b.
__global__ __launch_bounds__(256) void k3b_w2d(const unsigned int* __restrict__ hseq,
                                               const float* __restrict__ W2,
                                               const float* __restrict__ b2,
                                               float* __restrict__ D) {
  const int r0 = blockIdx.x * 16;   // rows (t*64+b); 16 rows share one t
  const int h = threadIdx.x;
  float acc[16];
  const float bias = b2[h];
#pragma unroll
  for (int r = 0; r < 16; ++r) acc[r] = bias;
  for (int m0 = 0; m0 < 128; m0 += 2) {   // 2 dwords = 4 k values
    const float w0 = W2[(size_t)(2 * m0 + 0) * 256 + h];
    const float w1 = W2[(size_t)(2 * m0 + 1) * 256 + h];
    const float w2 = W2[(size_t)(2 * m0 + 2) * 256 + h];
    const float w3 = W2[(size_t)(2 * m0 + 3) * 256 + h];
#pragma unroll
    for (int r = 0; r < 16; ++r) {
      const uint2 hp = *(const uint2*)&hseq[(size_t)(r0 + r) * 128 + m0];
      acc[r] = fmaf(bfbits2f(hp.x),       w0, acc[r]);   // h[2m0]   (low half)
      acc[r] = fmaf(bfbits2f(hp.x >> 16), w1, acc[r]);   // h[2m0+1] (high half)
      acc[r] = fmaf(bfbits2f(hp.y),       w2, acc[r]);   // h[2m0+2]
      acc[r] = fmaf(bfbits2f(hp.y >> 16), w3, acc[r]);   // h[2m0+3]
    }
  }
  const int t = r0 >> 6;
  const int bb0 = r0 & 63;
#pragma unroll
  for (int r = 0; r < 16; ++r) {
    D[((size_t)(bb0 + r) * 1024 + t) * 256 + h] = exp2f(C2LOG2E * acc[r]);
  }
}

// --- k4: attention scores + softmax.
// Block = (b, t-block of 16). Wave handles 4 t's; lane = l within 64-chunk; 16 chunks.
__global__ __launch_bounds__(256) void k4_attn(const unsigned short* __restrict__ AT,
                                               const float* __restrict__ Dm,
                                               const float* __restrict__ V,
                                               float* __restrict__ out) {
  const int b  = blockIdx.x >> 6;
  const int tb = blockIdx.x & 63;
  const int wv = threadIdx.x >> 6;
  const int lane = threadIdx.x & 63;
  const int t0 = tb * 16 + wv * 4;
  const unsigned short* Ab = AT + (size_t)b * 256 * 1024;
  const float* Db = Dm + ((size_t)b * 1024 + t0) * 256;
  float acc[4][16];
#pragma unroll
  for (int tt = 0; tt < 4; ++tt)
#pragma unroll
    for (int lb = 0; lb < 16; ++lb) acc[tt][lb] = 0.f;

  for (int h = 0; h < 256; ++h) {
    const float vh = V[h];
    const float d0 = Db[h];
    const float d1 = Db[256 + h];
    const float d2 = Db[512 + h];
    const float d3 = Db[768 + h];
    const unsigned short* Ah = Ab + h * 1024 + lane;
#pragma unroll
    for (int lb = 0; lb < 16; ++lb) {
      const float a = bfbits2f((unsigned)Ah[lb * 64]);
      acc[0][lb] = fmaf(vh, FAST_RCP(fmaf(a, d0, 1.f)), acc[0][lb]);
      acc[1][lb] = fmaf(vh, FAST_RCP(fmaf(a, d1, 1.f)), acc[1][lb]);
      acc[2][lb] = fmaf(vh, FAST_RCP(fmaf(a, d2, 1.f)), acc[2][lb]);
      acc[3][lb] = fmaf(vh, FAST_RCP(fmaf(a, d3, 1.f)), acc[3][lb]);
    }
  }
  // softmax over l (score = -2*acc; global constants cancel)
#pragma unroll
  for (int tt = 0; tt < 4; ++tt) {
    float s[16];
    float m = -1e30f;
#pragma unroll
    for (int lb = 0; lb < 16; ++lb) {
      s[lb] = -2.f * acc[tt][lb];
      m = fmaxf(m, s[lb]);
    }
    for (int off = 32; off > 0; off >>= 1) m = fmaxf(m, __shfl_xor(m, off, 64));
    float p[16];
    float sum = 0.f;
#pragma unroll
    for (int lb = 0; lb < 16; ++lb) {
      p[lb] = exp2f((s[lb] - m) * LOG2E);
      sum += p[lb];
    }
    for (int off = 32; off > 0; off >>= 1) sum += __shfl_xor(sum, off, 64);
    const float rs = 1.f / sum;
    float* op = out + ((size_t)(b * 1024) + (t0 + tt)) * 1024 + lane;
#pragma unroll
    for (int lb = 0; lb < 16; ++lb) op[lb * 64] = p[lb] * rs;
  }
}

// ---------------------------------------------------------------------------
extern "C" void kernel_launch(void* const* d_in, const int* in_sizes, int n_in,
                              void* d_out, int out_size, void* d_ws, size_t ws_size,
                              hipStream_t stream) {
  (void)in_sizes; (void)n_in; (void)out_size; (void)ws_size;
  const float* x  = (const float*)d_in[0];
  const float* Wk = (const float*)d_in[1];
  const float* Wr = (const float*)d_in[2];
  const float* bb = (const float*)d_in[3];
  const float* W1 = (const float*)d_in[4];
  const float* b1 = (const float*)d_in[5];
  const float* W2 = (const float*)d_in[6];
  const float* b2 = (const float*)d_in[7];
  const float* V  = (const float*)d_in[8];
  // d_in[9] = bV : constant over l, cancels in softmax.

  char* ws = (char*)d_ws;
  // Dm (64 MiB) @0 ALSO hosts Wrp2 (1 MiB) @0 earlier in the call:
  // k0 writes Wrp2 -> k3 reads it -> k3b overwrites region with Dm -> k4 reads Dm.
  // Same-stream kernel serialization makes this safe and deterministic.
  float*          Dm   = (float*)(ws);                          // 64 MiB f32 D[b][t][h]
  float*          Wrp2 = (float*)(ws);                          // 1 MiB f32 Wr pairs (transient)
  unsigned short* AT   = (unsigned short*)(ws + 67108864);      // 32 MiB bf16 A[b][h][l]
  unsigned short* hseq = (unsigned short*)(ws + 100663296);     // 32 MiB bf16 h_t
  float*          xz   = (float*)(ws + 134217728);              // 256 KiB
  float* out = (float*)d_out;

  hipLaunchKernelGGL(k0_pack, dim3(512), dim3(256), 0, stream, Wr, Wrp2);
  hipLaunchKernelGGL(k1_w1e, dim3(4096), dim3(256), 0, stream, x, W1, b1, AT);
  hipLaunchKernelGGL(k2_xz, dim3(64), dim3(256), 0, stream, x, Wk, bb, xz);
  hipLaunchKernelGGL(k3_recur, dim3(64), dim3(512), 0, stream, xz, Wrp2, hseq);
  hipLaunchKernelGGL(k3b_w2d, dim3(4096), dim3(256), 0, stream, (const unsigned int*)hseq, W2, b2, Dm);
  hipLaunchKernelGGL(k4_attn, dim3(4096), dim3(256), 0, stream, AT, Dm, V, out);
}

// Round 5
// 4868.842 us; speedup vs baseline: 2.1415x; 2.1415x over previous
//
#include <hip/hip_runtime.h>
#include <hip/hip_bf16.h>

// ---------------------------------------------------------------------------
// PointerLSTM: B=64, L=1024, D=256, H=256, T=1024 steps.
//   tanh(x) = 1 - 2/(1 + e^{2x});  e^{2(a+d)} = A*D with A=e^{2a}, D=e^{2d}
//   score_l = const - 2*sum_h V_h/(1+A_lh*D_th)   -> const cancels in softmax
// R4 -> R5: k3 was per-CU L2-BW-bound (1 MiB Wr streamed per step = 18.7k cy,
// measured 7.77us/step). Now Wr is CU-RESIDENT: bf16 pairs, 104/col in VGPRs +
// 24/col in LDS. h exchanged as bf16x2 in LDS (R1==R3 absmax proves bf16-loop
// error is negligible). No weight streaming at all.
// ---------------------------------------------------------------------------

#define LOG2E  1.4426950408889634f
#define C2LOG2E 2.8853900817779268f   // 2*log2(e)

__device__ __forceinline__ unsigned f2bf(float f) {
  unsigned u = __builtin_bit_cast(unsigned, f);
  return (u + 0x7fffu + ((u >> 16) & 1u)) >> 16;   // round-to-nearest-even
}
// bf16 bits in the LOW half of `bits` -> float. (High half ignored.)
__device__ __forceinline__ float bfbits2f(unsigned bits) {
  return __builtin_bit_cast(float, bits << 16);
}

#if defined(__has_builtin)
#  if __has_builtin(__builtin_amdgcn_fdot2_f32_bf16)
#    define HAS_DOT2_BF16 1
#  endif
#endif

#if defined(HAS_DOT2_BF16)
typedef __bf16 bf16x2v __attribute__((ext_vector_type(2)));
__device__ __forceinline__ float dot2bf(unsigned w, unsigned h, float acc) {
  return __builtin_amdgcn_fdot2_f32_bf16(__builtin_bit_cast(bf16x2v, w),
                                         __builtin_bit_cast(bf16x2v, h), acc, false);
}
#else
__device__ __forceinline__ float dot2bf(unsigned w, unsigned h, float acc) {
  float wl = __builtin_bit_cast(float, w << 16);
  float wh = __builtin_bit_cast(float, w & 0xffff0000u);
  float hl = __builtin_bit_cast(float, h << 16);
  float hh = __builtin_bit_cast(float, h & 0xffff0000u);
  return fmaf(wh, hh, fmaf(wl, hl, acc));
}
#endif

#if defined(__has_builtin) && __has_builtin(__builtin_amdgcn_rcpf)
#  define FAST_RCP(x) __builtin_amdgcn_rcpf(x)
#else
#  define FAST_RCP(x) (1.0f / (x))
#endif

// --- k1: w1e = x@W1 + b1 ; store AT[b][h][l] = bf16(exp2(C2*w1e))   (transposed!)
__global__ __launch_bounds__(256) void k1_w1e(const float* __restrict__ x,
                                              const float* __restrict__ W1,
                                              const float* __restrict__ b1,
                                              unsigned short* __restrict__ AT) {
  const int b  = blockIdx.x >> 6;
  const int lb = blockIdx.x & 63;   // 16 l-rows per block
  const int h  = threadIdx.x;
  float acc[16];
  const float bias = b1[h];
#pragma unroll
  for (int r = 0; r < 16; ++r) acc[r] = bias;
  const float* xb = x + ((size_t)(b * 1024 + lb * 16)) * 256;
  for (int d0 = 0; d0 < 256; d0 += 4) {
    const float w0 = W1[(d0 + 0) * 256 + h];
    const float w1 = W1[(d0 + 1) * 256 + h];
    const float w2 = W1[(d0 + 2) * 256 + h];
    const float w3 = W1[(d0 + 3) * 256 + h];
#pragma unroll
    for (int r = 0; r < 16; ++r) {
      const float4 xv = *(const float4*)(xb + r * 256 + d0);
      acc[r] = fmaf(xv.x, w0, acc[r]);
      acc[r] = fmaf(xv.y, w1, acc[r]);
      acc[r] = fmaf(xv.z, w2, acc[r]);
      acc[r] = fmaf(xv.w, w3, acc[r]);
    }
  }
  unsigned short* outp = AT + ((size_t)(b * 256 + h)) * 1024 + lb * 16;
#pragma unroll
  for (int r = 0; r < 16; r += 2) {
    unsigned u0 = f2bf(exp2f(C2LOG2E * acc[r]));
    unsigned u1 = f2bf(exp2f(C2LOG2E * acc[r + 1]));
    *(unsigned*)(outp + r) = u0 | (u1 << 16);
  }
}

// --- k2: xz[b][j] = x[b][1023][:] @ Wk[:,j] + b[j]
__global__ __launch_bounds__(256) void k2_xz(const float* __restrict__ x,
                                             const float* __restrict__ Wk,
                                             const float* __restrict__ bvec,
                                             float* __restrict__ xz) {
  const int b = blockIdx.x, tid = threadIdx.x;
  float acc[4] = {bvec[tid], bvec[256 + tid], bvec[512 + tid], bvec[768 + tid]};
  const float* xr = x + ((size_t)b * 1024 + 1023) * 256;
  for (int d0 = 0; d0 < 256; d0 += 4) {
    const float4 xv = *(const float4*)(xr + d0);
#pragma unroll
    for (int i = 0; i < 4; ++i) {
      const float xs = (i == 0) ? xv.x : (i == 1) ? xv.y : (i == 2) ? xv.z : xv.w;
#pragma unroll
      for (int q = 0; q < 4; ++q)
        acc[q] = fmaf(xs, Wk[(size_t)(d0 + i) * 1024 + q * 256 + tid], acc[q]);
    }
  }
#pragma unroll
  for (int q = 0; q < 4; ++q) xz[b * 1024 + q * 256 + tid] = acc[q];
}

// --- k3: sequential LSTM recurrence. ONE WG (512 threads) per batch.
// Thread owns columns (tid, tid+512). Weights as bf16x2 row-pairs:
//   pairs 0..103  in VGPRs (104 x 2 cols = 208 regs)
//   pairs 104..127 in LDS   (24 pairs x 1024 cols x 4B = 96 KiB), layout
//   Wtail[gg][col][d] so a b128 read per (group,col) is lane-contiguous.
// h kept as bf16x2 in LDS h_pk[128], broadcast-read by all threads.
// Gates: threads 0..127 handle h-indices (2*tid, 2*tid+1), write h_pk + hseq.
__global__ __launch_bounds__(512) void k3_recur(const float* __restrict__ xz,
                                                const float* __restrict__ Wr,
                                                unsigned short* __restrict__ hseq) {
  __shared__ __align__(16) unsigned Wtail[6 * 1024 * 4];  // 96 KiB
  __shared__ float z_lds[1024];
  __shared__ __align__(16) unsigned h_pk[128];
  const int b   = blockIdx.x;
  const int tid = threadIdx.x;
  const int colA = tid, colB = tid + 512;

  unsigned wA[104], wB[104];
#pragma unroll
  for (int p = 0; p < 104; ++p) {
    wA[p] = f2bf(Wr[(size_t)(2 * p) * 1024 + colA]) |
            (f2bf(Wr[(size_t)(2 * p + 1) * 1024 + colA]) << 16);
    wB[p] = f2bf(Wr[(size_t)(2 * p) * 1024 + colB]) |
            (f2bf(Wr[(size_t)(2 * p + 1) * 1024 + colB]) << 16);
  }
#pragma unroll
  for (int gg = 0; gg < 6; ++gg) {
#pragma unroll
    for (int d = 0; d < 4; ++d) {
      const int p = 104 + gg * 4 + d;
      Wtail[(gg * 1024 + colA) * 4 + d] =
          f2bf(Wr[(size_t)(2 * p) * 1024 + colA]) |
          (f2bf(Wr[(size_t)(2 * p + 1) * 1024 + colA]) << 16);
      Wtail[(gg * 1024 + colB) * 4 + d] =
          f2bf(Wr[(size_t)(2 * p) * 1024 + colB]) |
          (f2bf(Wr[(size_t)(2 * p + 1) * 1024 + colB]) << 16);
    }
  }
  if (tid < 128) h_pk[tid] = 0u;
  const float zaA = xz[b * 1024 + colA];
  const float zaB = xz[b * 1024 + colB];
  float c0 = 0.f, c1 = 0.f;
  __syncthreads();

  for (int t = 0; t < 1024; ++t) {
    float aA = zaA, aB = zaB;
#pragma unroll
    for (int g4 = 0; g4 < 26; ++g4) {
      const uint4 hp = *(const uint4*)&h_pk[4 * g4];
      aA = dot2bf(wA[4 * g4 + 0], hp.x, aA);
      aA = dot2bf(wA[4 * g4 + 1], hp.y, aA);
      aA = dot2bf(wA[4 * g4 + 2], hp.z, aA);
      aA = dot2bf(wA[4 * g4 + 3], hp.w, aA);
      aB = dot2bf(wB[4 * g4 + 0], hp.x, aB);
      aB = dot2bf(wB[4 * g4 + 1], hp.y, aB);
      aB = dot2bf(wB[4 * g4 + 2], hp.z, aB);
      aB = dot2bf(wB[4 * g4 + 3], hp.w, aB);
    }
#pragma unroll
    for (int gg = 0; gg < 6; ++gg) {
      const uint4 hp = *(const uint4*)&h_pk[104 + 4 * gg];
      const uint4 wa = *(const uint4*)&Wtail[(gg * 1024 + colA) * 4];
      const uint4 wb = *(const uint4*)&Wtail[(gg * 1024 + colB) * 4];
      aA = dot2bf(wa.x, hp.x, aA);
      aA = dot2bf(wa.y, hp.y, aA);
      aA = dot2bf(wa.z, hp.z, aA);
      aA = dot2bf(wa.w, hp.w, aA);
      aB = dot2bf(wb.x, hp.x, aB);
      aB = dot2bf(wb.y, hp.y, aB);
      aB = dot2bf(wb.z, hp.z, aB);
      aB = dot2bf(wb.w, hp.w, aB);
    }
    z_lds[colA] = aA;
    z_lds[colB] = aB;
    __syncthreads();
    if (tid < 128) {
      float hh[2];
#pragma unroll
      for (int e = 0; e < 2; ++e) {
        const int hi = 2 * tid + e;
        const float zi = z_lds[hi];
        const float zf = z_lds[256 + hi];
        const float zg = z_lds[512 + hi];
        const float zo = z_lds[768 + hi];
        const float ig = 1.f / (1.f + expf(-zi));
        const float fg = 1.f / (1.f + expf(-zf));
        const float gv = tanhf(zg);
        const float og = 1.f / (1.f + expf(-zo));
        float& cc = e ? c1 : c0;
        cc = fmaf(fg, cc, ig * gv);
        hh[e] = og * tanhf(cc);
      }
      const unsigned pk = f2bf(hh[0]) | (f2bf(hh[1]) << 16);
      h_pk[tid] = pk;
      *(unsigned*)&hseq[(size_t)(t * 64 + b) * 256 + 2 * tid] = pk;
    }
    __syncthreads();
  }
}

// --- k3b: w2d = hseq @ W2 + b2 for all (t,b); store D[b][t][h] = f32(exp2(C2*w2d))
// hseq dword m = (h[2m] in LOW half, h[2m+1] in HIGH half), row = t*64+b.
__global__ __launch_bounds__(256) void k3b_w2d(const unsigned int* __restrict__ hseq,
                                               const float* __restrict__ W2,
                                               const float* __restrict__ b2,
                                               float* __restrict__ D) {
  const int r0 = blockIdx.x * 16;   // rows (t*64+b); 16 rows share one t
  const int h = threadIdx.x;
  float acc[16];
  const float bias = b2[h];
#pragma unroll
  for (int r = 0; r < 16; ++r) acc[r] = bias;
  for (int m0 = 0; m0 < 128; m0 += 2) {   // 2 dwords = 4 k values
    const float w0 = W2[(size_t)(2 * m0 + 0) * 256 + h];
    const float w1 = W2[(size_t)(2 * m0 + 1) * 256 + h];
    const float w2 = W2[(size_t)(2 * m0 + 2) * 256 + h];
    const float w3 = W2[(size_t)(2 * m0 + 3) * 256 + h];
#pragma unroll
    for (int r = 0; r < 16; ++r) {
      const uint2 hp = *(const uint2*)&hseq[(size_t)(r0 + r) * 128 + m0];
      acc[r] = fmaf(bfbits2f(hp.x),       w0, acc[r]);   // h[2m0]   (low half)
      acc[r] = fmaf(bfbits2f(hp.x >> 16), w1, acc[r]);   // h[2m0+1] (high half)
      acc[r] = fmaf(bfbits2f(hp.y),       w2, acc[r]);   // h[2m0+2]
      acc[r] = fmaf(bfbits2f(hp.y >> 16), w3, acc[r]);   // h[2m0+3]
    }
  }
  const int t = r0 >> 6;
  const int bb0 = r0 & 63;
#pragma unroll
  for (int r = 0; r < 16; ++r) {
    D[((size_t)(bb0 + r) * 1024 + t) * 256 + h] = exp2f(C2LOG2E * acc[r]);
  }
}

// --- k4: attention scores + softmax.
// Block = (b, t-block of 16). Wave handles 4 t's; lane = l within 64-chunk; 16 chunks.
__global__ __launch_bounds__(256) void k4_attn(const unsigned short* __restrict__ AT,
                                               const float* __restrict__ Dm,
                                               const float* __restrict__ V,
                                               float* __restrict__ out) {
  const int b  = blockIdx.x >> 6;
  const int tb = blockIdx.x & 63;
  const int wv = threadIdx.x >> 6;
  const int lane = threadIdx.x & 63;
  const int t0 = tb * 16 + wv * 4;
  const unsigned short* Ab = AT + (size_t)b * 256 * 1024;
  const float* Db = Dm + ((size_t)b * 1024 + t0) * 256;
  float acc[4][16];
#pragma unroll
  for (int tt = 0; tt < 4; ++tt)
#pragma unroll
    for (int lb = 0; lb < 16; ++lb) acc[tt][lb] = 0.f;

  for (int h = 0; h < 256; ++h) {
    const float vh = V[h];
    const float d0 = Db[h];
    const float d1 = Db[256 + h];
    const float d2 = Db[512 + h];
    const float d3 = Db[768 + h];
    const unsigned short* Ah = Ab + h * 1024 + lane;
#pragma unroll
    for (int lb = 0; lb < 16; ++lb) {
      const float a = bfbits2f((unsigned)Ah[lb * 64]);
      acc[0][lb] = fmaf(vh, FAST_RCP(fmaf(a, d0, 1.f)), acc[0][lb]);
      acc[1][lb] = fmaf(vh, FAST_RCP(fmaf(a, d1, 1.f)), acc[1][lb]);
      acc[2][lb] = fmaf(vh, FAST_RCP(fmaf(a, d2, 1.f)), acc[2][lb]);
      acc[3][lb] = fmaf(vh, FAST_RCP(fmaf(a, d3, 1.f)), acc[3][lb]);
    }
  }
  // softmax over l (score = -2*acc; global constants cancel)
#pragma unroll
  for (int tt = 0; tt < 4; ++tt) {
    float s[16];
    float m = -1e30f;
#pragma unroll
    for (int lb = 0; lb < 16; ++lb) {
      s[lb] = -2.f * acc[tt][lb];
      m = fmaxf(m, s[lb]);
    }
    for (int off = 32; off > 0; off >>= 1) m = fmaxf(m, __shfl_xor(m, off, 64));
    float p[16];
    float sum = 0.f;
#pragma unroll
    for (int lb = 0; lb < 16; ++lb) {
      p[lb] = exp2f((s[lb] - m) * LOG2E);
      sum += p[lb];
    }
    for (int off = 32; off > 0; off >>= 1) sum += __shfl_xor(sum, off, 64);
    const float rs = 1.f / sum;
    float* op = out + ((size_t)(b * 1024) + (t0 + tt)) * 1024 + lane;
#pragma unroll
    for (int lb = 0; lb < 16; ++lb) op[lb * 64] = p[lb] * rs;
  }
}

// ---------------------------------------------------------------------------
extern "C" void kernel_launch(void* const* d_in, const int* in_sizes, int n_in,
                              void* d_out, int out_size, void* d_ws, size_t ws_size,
                              hipStream_t stream) {
  (void)in_sizes; (void)n_in; (void)out_size; (void)ws_size;
  const float* x  = (const float*)d_in[0];
  const float* Wk = (const float*)d_in[1];
  const float* Wr = (const float*)d_in[2];
  const float* bb = (const float*)d_in[3];
  const float* W1 = (const float*)d_in[4];
  const float* b1 = (const float*)d_in[5];
  const float* W2 = (const float*)d_in[6];
  const float* b2 = (const float*)d_in[7];
  const float* V  = (const float*)d_in[8];
  // d_in[9] = bV : constant over l, cancels in softmax.

  char* ws = (char*)d_ws;
  float*          Dm   = (float*)(ws);                          // 64 MiB f32 D[b][t][h]
  unsigned short* AT   = (unsigned short*)(ws + 67108864);      // 32 MiB bf16 A[b][h][l]
  unsigned short* hseq = (unsigned short*)(ws + 100663296);     // 32 MiB bf16 h_t
  float*          xz   = (float*)(ws + 134217728);              // 256 KiB
  float* out = (float*)d_out;

  hipLaunchKernelGGL(k1_w1e, dim3(4096), dim3(256), 0, stream, x, W1, b1, AT);
  hipLaunchKernelGGL(k2_xz, dim3(64), dim3(256), 0, stream, x, Wk, bb, xz);
  hipLaunchKernelGGL(k3_recur, dim3(64), dim3(512), 0, stream, xz, Wr, hseq);
  hipLaunchKernelGGL(k3b_w2d, dim3(4096), dim3(256), 0, stream, (const unsigned int*)hseq, W2, b2, Dm);
  hipLaunchKernelGGL(k4_attn, dim3(4096), dim3(256), 0, stream, AT, Dm, V, out);
}

// Round 6
// 4266.425 us; speedup vs baseline: 2.4439x; 1.1412x over previous
//
#include <hip/hip_runtime.h>
#include <hip/hip_bf16.h>

// ---------------------------------------------------------------------------
// PointerLSTM: B=64, L=1024, D=256, H=256, T=1024 steps.
//   tanh(x) = 1 - 2/(1 + e^{2x});  e^{2(a+d)} = A*D with A=e^{2a}, D=e^{2d}
//   score_l = const - 2*sum_h V_h/(1+A_lh*D_th)   -> const cancels in softmax
// R5 -> R6: k3's weight arrays SPILLED (VGPR_Count=128; launch_bounds had no
// waves/EU arg). Now __launch_bounds__(512,2) -> 256 VGPR cap; 96 bf16-pairs
// per column in VGPRs (192 regs) + 32 pairs in LDS (128 KiB). z exchange
// halved (thread owns its own z_i and z_g); gates on 4 waves w/ exp2+rcp.
// ---------------------------------------------------------------------------

#define LOG2E  1.4426950408889634f
#define C2LOG2E 2.8853900817779268f   // 2*log2(e)

__device__ __forceinline__ unsigned f2bf(float f) {
  unsigned u = __builtin_bit_cast(unsigned, f);
  return (u + 0x7fffu + ((u >> 16) & 1u)) >> 16;   // round-to-nearest-even
}
// bf16 bits in the LOW half of `bits` -> float. (High half ignored.)
__device__ __forceinline__ float bfbits2f(unsigned bits) {
  return __builtin_bit_cast(float, bits << 16);
}

#if defined(__has_builtin)
#  if __has_builtin(__builtin_amdgcn_fdot2_f32_bf16)
#    define HAS_DOT2_BF16 1
#  endif
#endif

#if defined(HAS_DOT2_BF16)
typedef __bf16 bf16x2v __attribute__((ext_vector_type(2)));
__device__ __forceinline__ float dot2bf(unsigned w, unsigned h, float acc) {
  return __builtin_amdgcn_fdot2_f32_bf16(__builtin_bit_cast(bf16x2v, w),
                                         __builtin_bit_cast(bf16x2v, h), acc, false);
}
#else
__device__ __forceinline__ float dot2bf(unsigned w, unsigned h, float acc) {
  float wl = __builtin_bit_cast(float, w << 16);
  float wh = __builtin_bit_cast(float, w & 0xffff0000u);
  float hl = __builtin_bit_cast(float, h << 16);
  float hh = __builtin_bit_cast(float, h & 0xffff0000u);
  return fmaf(wh, hh, fmaf(wl, hl, acc));
}
#endif

#if defined(__has_builtin) && __has_builtin(__builtin_amdgcn_rcpf)
#  define FAST_RCP(x) __builtin_amdgcn_rcpf(x)
#else
#  define FAST_RCP(x) (1.0f / (x))
#endif

__device__ __forceinline__ float fast_sigmoid(float x) {
  return FAST_RCP(1.f + exp2f(-LOG2E * x));
}
__device__ __forceinline__ float fast_tanh(float x) {
  return 1.f - 2.f * FAST_RCP(1.f + exp2f(C2LOG2E * x));
}

// --- k1: w1e = x@W1 + b1 ; store AT[b][h][l] = bf16(exp2(C2*w1e))   (transposed!)
__global__ __launch_bounds__(256) void k1_w1e(const float* __restrict__ x,
                                              const float* __restrict__ W1,
                                              const float* __restrict__ b1,
                                              unsigned short* __restrict__ AT) {
  const int b  = blockIdx.x >> 6;
  const int lb = blockIdx.x & 63;   // 16 l-rows per block
  const int h  = threadIdx.x;
  float acc[16];
  const float bias = b1[h];
#pragma unroll
  for (int r = 0; r < 16; ++r) acc[r] = bias;
  const float* xb = x + ((size_t)(b * 1024 + lb * 16)) * 256;
  for (int d0 = 0; d0 < 256; d0 += 4) {
    const float w0 = W1[(d0 + 0) * 256 + h];
    const float w1 = W1[(d0 + 1) * 256 + h];
    const float w2 = W1[(d0 + 2) * 256 + h];
    const float w3 = W1[(d0 + 3) * 256 + h];
#pragma unroll
    for (int r = 0; r < 16; ++r) {
      const float4 xv = *(const float4*)(xb + r * 256 + d0);
      acc[r] = fmaf(xv.x, w0, acc[r]);
      acc[r] = fmaf(xv.y, w1, acc[r]);
      acc[r] = fmaf(xv.z, w2, acc[r]);
      acc[r] = fmaf(xv.w, w3, acc[r]);
    }
  }
  unsigned short* outp = AT + ((size_t)(b * 256 + h)) * 1024 + lb * 16;
#pragma unroll
  for (int r = 0; r < 16; r += 2) {
    unsigned u0 = f2bf(exp2f(C2LOG2E * acc[r]));
    unsigned u1 = f2bf(exp2f(C2LOG2E * acc[r + 1]));
    *(unsigned*)(outp + r) = u0 | (u1 << 16);
  }
}

// --- k2: xz[b][j] = x[b][1023][:] @ Wk[:,j] + b[j]
__global__ __launch_bounds__(256) void k2_xz(const float* __restrict__ x,
                                             const float* __restrict__ Wk,
                                             const float* __restrict__ bvec,
                                             float* __restrict__ xz) {
  const int b = blockIdx.x, tid = threadIdx.x;
  float acc[4] = {bvec[tid], bvec[256 + tid], bvec[512 + tid], bvec[768 + tid]};
  const float* xr = x + ((size_t)b * 1024 + 1023) * 256;
  for (int d0 = 0; d0 < 256; d0 += 4) {
    const float4 xv = *(const float4*)(xr + d0);
#pragma unroll
    for (int i = 0; i < 4; ++i) {
      const float xs = (i == 0) ? xv.x : (i == 1) ? xv.y : (i == 2) ? xv.z : xv.w;
#pragma unroll
      for (int q = 0; q < 4; ++q)
        acc[q] = fmaf(xs, Wk[(size_t)(d0 + i) * 1024 + q * 256 + tid], acc[q]);
    }
  }
#pragma unroll
  for (int q = 0; q < 4; ++q) xz[b * 1024 + q * 256 + tid] = acc[q];
}

// --- k3: sequential LSTM recurrence. ONE WG (512 threads, 2 waves/EU) per batch.
// Thread owns columns (tid, tid+512). Weight bf16x2 row-pairs:
//   pairs 0..95   in VGPRs (96 x 2 cols = 192 regs)
//   pairs 96..127 in LDS   (32 pairs x 1024 cols x 4B = 128 KiB)
// h as bf16x2 in LDS h_pk[128] (uniform b128 reads).
// Gate split by column ownership: thread tid<256 owns z_i(=its colA) and
// z_g(=its colB); threads 256..511 export z_f,z_o via z_lds. Gates: 1 elem
// per thread on threads 0..255 (4 waves), c persists in-register.
__global__ __launch_bounds__(512, 2) void k3_recur(const float* __restrict__ xz,
                                                   const float* __restrict__ Wr,
                                                   unsigned short* __restrict__ hseq) {
  __shared__ __align__(16) unsigned Wtail[8 * 1024 * 4];  // 128 KiB, pairs 96..127
  __shared__ float z_lds[512];                            // zf, zo exchange
  __shared__ __align__(16) unsigned h_pk[128];            // h as bf16x2
  const int b   = blockIdx.x;
  const int tid = threadIdx.x;
  const int colA = tid, colB = tid + 512;

  unsigned wA[96], wB[96];
#pragma unroll
  for (int p = 0; p < 96; ++p) {
    wA[p] = f2bf(Wr[(size_t)(2 * p) * 1024 + colA]) |
            (f2bf(Wr[(size_t)(2 * p + 1) * 1024 + colA]) << 16);
    wB[p] = f2bf(Wr[(size_t)(2 * p) * 1024 + colB]) |
            (f2bf(Wr[(size_t)(2 * p + 1) * 1024 + colB]) << 16);
  }
#pragma unroll
  for (int gg = 0; gg < 8; ++gg) {
#pragma unroll
    for (int d = 0; d < 4; ++d) {
      const int p = 96 + gg * 4 + d;
      Wtail[(gg * 1024 + colA) * 4 + d] =
          f2bf(Wr[(size_t)(2 * p) * 1024 + colA]) |
          (f2bf(Wr[(size_t)(2 * p + 1) * 1024 + colA]) << 16);
      Wtail[(gg * 1024 + colB) * 4 + d] =
          f2bf(Wr[(size_t)(2 * p) * 1024 + colB]) |
          (f2bf(Wr[(size_t)(2 * p + 1) * 1024 + colB]) << 16);
    }
  }
  if (tid < 128) h_pk[tid] = 0u;
  const float zaA = xz[b * 1024 + colA];
  const float zaB = xz[b * 1024 + colB];
  float c = 0.f;
  __syncthreads();

  for (int t = 0; t < 1024; ++t) {
    float aA = zaA, aB = zaB;
#pragma unroll
    for (int g = 0; g < 24; ++g) {
      const uint4 hp = *(const uint4*)&h_pk[4 * g];
      aA = dot2bf(wA[4 * g + 0], hp.x, aA);
      aA = dot2bf(wA[4 * g + 1], hp.y, aA);
      aA = dot2bf(wA[4 * g + 2], hp.z, aA);
      aA = dot2bf(wA[4 * g + 3], hp.w, aA);
      aB = dot2bf(wB[4 * g + 0], hp.x, aB);
      aB = dot2bf(wB[4 * g + 1], hp.y, aB);
      aB = dot2bf(wB[4 * g + 2], hp.z, aB);
      aB = dot2bf(wB[4 * g + 3], hp.w, aB);
    }
#pragma unroll
    for (int gg = 0; gg < 8; ++gg) {
      const uint4 hp = *(const uint4*)&h_pk[96 + 4 * gg];
      const uint4 wa = *(const uint4*)&Wtail[(gg * 1024 + colA) * 4];
      const uint4 wb = *(const uint4*)&Wtail[(gg * 1024 + colB) * 4];
      aA = dot2bf(wa.x, hp.x, aA);
      aA = dot2bf(wa.y, hp.y, aA);
      aA = dot2bf(wa.z, hp.z, aA);
      aA = dot2bf(wa.w, hp.w, aA);
      aB = dot2bf(wb.x, hp.x, aB);
      aB = dot2bf(wb.y, hp.y, aB);
      aB = dot2bf(wb.z, hp.z, aB);
      aB = dot2bf(wb.w, hp.w, aB);
    }
    // z export: thread>=256 holds zf (colA in [256,512)) and zo (colB in [768,1024))
    if (tid >= 256) {
      z_lds[tid - 256] = aA;        // zf for h-elem (tid-256)
      z_lds[tid]       = aB;        // zo for h-elem (tid-256), offset +256
    }
    __syncthreads();
    // gates: thread<256 owns h-elem tid; zi = own colA, zg = own colB.
    if (tid < 256) {
      const float zi = aA;
      const float zg = aB;
      const float zf = z_lds[tid];
      const float zo = z_lds[tid + 256];
      const float ig = fast_sigmoid(zi);
      const float fg = fast_sigmoid(zf);
      const float gv = fast_tanh(zg);
      const float og = fast_sigmoid(zo);
      c = fmaf(fg, c, ig * gv);
      const float h = og * fast_tanh(c);
      const unsigned short hb = (unsigned short)f2bf(h);
      ((unsigned short*)h_pk)[tid] = hb;
      hseq[(size_t)(t * 64 + b) * 256 + tid] = hb;
    }
    __syncthreads();
  }
}

// --- k3b: w2d = hseq @ W2 + b2 for all (t,b); store D[b][t][h] = f32(exp2(C2*w2d))
// hseq dword m = (h[2m] in LOW half, h[2m+1] in HIGH half), row = t*64+b.
__global__ __launch_bounds__(256) void k3b_w2d(const unsigned int* __restrict__ hseq,
                                               const float* __restrict__ W2,
                                               const float* __restrict__ b2,
                                               float* __restrict__ D) {
  const int r0 = blockIdx.x * 16;   // rows (t*64+b); 16 rows share one t
  const int h = threadIdx.x;
  float acc[16];
  const float bias = b2[h];
#pragma unroll
  for (int r = 0; r < 16; ++r) acc[r] = bias;
  for (int m0 = 0; m0 < 128; m0 += 2) {   // 2 dwords = 4 k values
    const float w0 = W2[(size_t)(2 * m0 + 0) * 256 + h];
    const float w1 = W2[(size_t)(2 * m0 + 1) * 256 + h];
    const float w2 = W2[(size_t)(2 * m0 + 2) * 256 + h];
    const float w3 = W2[(size_t)(2 * m0 + 3) * 256 + h];
#pragma unroll
    for (int r = 0; r < 16; ++r) {
      const uint2 hp = *(const uint2*)&hseq[(size_t)(r0 + r) * 128 + m0];
      acc[r] = fmaf(bfbits2f(hp.x),       w0, acc[r]);   // h[2m0]   (low half)
      acc[r] = fmaf(bfbits2f(hp.x >> 16), w1, acc[r]);   // h[2m0+1] (high half)
      acc[r] = fmaf(bfbits2f(hp.y),       w2, acc[r]);   // h[2m0+2]
      acc[r] = fmaf(bfbits2f(hp.y >> 16), w3, acc[r]);   // h[2m0+3]
    }
  }
  const int t = r0 >> 6;
  const int bb0 = r0 & 63;
#pragma unroll
  for (int r = 0; r < 16; ++r) {
    D[((size_t)(bb0 + r) * 1024 + t) * 256 + h] = exp2f(C2LOG2E * acc[r]);
  }
}

// --- k4: attention scores + softmax.
// Block = (b, t-block of 16). Wave handles 4 t's; lane = l within 64-chunk; 16 chunks.
__global__ __launch_bounds__(256) void k4_attn(const unsigned short* __restrict__ AT,
                                               const float* __restrict__ Dm,
                                               const float* __restrict__ V,
                                               float* __restrict__ out) {
  const int b  = blockIdx.x >> 6;
  const int tb = blockIdx.x & 63;
  const int wv = threadIdx.x >> 6;
  const int lane = threadIdx.x & 63;
  const int t0 = tb * 16 + wv * 4;
  const unsigned short* Ab = AT + (size_t)b * 256 * 1024;
  const float* Db = Dm + ((size_t)b * 1024 + t0) * 256;
  float acc[4][16];
#pragma unroll
  for (int tt = 0; tt < 4; ++tt)
#pragma unroll
    for (int lb = 0; lb < 16; ++lb) acc[tt][lb] = 0.f;

  for (int h = 0; h < 256; ++h) {
    const float vh = V[h];
    const float d0 = Db[h];
    const float d1 = Db[256 + h];
    const float d2 = Db[512 + h];
    const float d3 = Db[768 + h];
    const unsigned short* Ah = Ab + h * 1024 + lane;
#pragma unroll
    for (int lb = 0; lb < 16; ++lb) {
      const float a = bfbits2f((unsigned)Ah[lb * 64]);
      acc[0][lb] = fmaf(vh, FAST_RCP(fmaf(a, d0, 1.f)), acc[0][lb]);
      acc[1][lb] = fmaf(vh, FAST_RCP(fmaf(a, d1, 1.f)), acc[1][lb]);
      acc[2][lb] = fmaf(vh, FAST_RCP(fmaf(a, d2, 1.f)), acc[2][lb]);
      acc[3][lb] = fmaf(vh, FAST_RCP(fmaf(a, d3, 1.f)), acc[3][lb]);
    }
  }
  // softmax over l (score = -2*acc; global constants cancel)
#pragma unroll
  for (int tt = 0; tt < 4; ++tt) {
    float s[16];
    float m = -1e30f;
#pragma unroll
    for (int lb = 0; lb < 16; ++lb) {
      s[lb] = -2.f * acc[tt][lb];
      m = fmaxf(m, s[lb]);
    }
    for (int off = 32; off > 0; off >>= 1) m = fmaxf(m, __shfl_xor(m, off, 64));
    float p[16];
    float sum = 0.f;
#pragma unroll
    for (int lb = 0; lb < 16; ++lb) {
      p[lb] = exp2f((s[lb] - m) * LOG2E);
      sum += p[lb];
    }
    for (int off = 32; off > 0; off >>= 1) sum += __shfl_xor(sum, off, 64);
    const float rs = 1.f / sum;
    float* op = out + ((size_t)(b * 1024) + (t0 + tt)) * 1024 + lane;
#pragma unroll
    for (int lb = 0; lb < 16; ++lb) op[lb * 64] = p[lb] * rs;
  }
}

// ---------------------------------------------------------------------------
extern "C" void kernel_launch(void* const* d_in, const int* in_sizes, int n_in,
                              void* d_out, int out_size, void* d_ws, size_t ws_size,
                              hipStream_t stream) {
  (void)in_sizes; (void)n_in; (void)out_size; (void)ws_size;
  const float* x  = (const float*)d_in[0];
  const float* Wk = (const float*)d_in[1];
  const float* Wr = (const float*)d_in[2];
  const float* bb = (const float*)d_in[3];
  const float* W1 = (const float*)d_in[4];
  const float* b1 = (const float*)d_in[5];
  const float* W2 = (const float*)d_in[6];
  const float* b2 = (const float*)d_in[7];
  const float* V  = (const float*)d_in[8];
  // d_in[9] = bV : constant over l, cancels in softmax.

  char* ws = (char*)d_ws;
  float*          Dm   = (float*)(ws);                          // 64 MiB f32 D[b][t][h]
  unsigned short* AT   = (unsigned short*)(ws + 67108864);      // 32 MiB bf16 A[b][h][l]
  unsigned short* hseq = (unsigned short*)(ws + 100663296);     // 32 MiB bf16 h_t
  float*          xz   = (float*)(ws + 134217728);              // 256 KiB
  float* out = (float*)d_out;

  hipLaunchKernelGGL(k1_w1e, dim3(4096), dim3(256), 0, stream, x, W1, b1, AT);
  hipLaunchKernelGGL(k2_xz, dim3(64), dim3(256), 0, stream, x, Wk, bb, xz);
  hipLaunchKernelGGL(k3_recur, dim3(64), dim3(512), 0, stream, xz, Wr, hseq);
  hipLaunchKernelGGL(k3b_w2d, dim3(4096), dim3(256), 0, stream, (const unsigned int*)hseq, W2, b2, Dm);
  hipLaunchKernelGGL(k4_attn, dim3(4096), dim3(256), 0, stream, AT, Dm, V, out);
}

// Round 7
// 4165.744 us; speedup vs baseline: 2.5030x; 1.0242x over previous
//
#include <hip/hip_runtime.h>
#include <hip/hip_bf16.h>

// ---------------------------------------------------------------------------
// PointerLSTM: B=64, L=1024, D=256, H=256, T=1024 steps.
//   tanh(x) = 1 - 2/(1 + e^{2x});  e^{2(a+d)} = A*D with A=e^{2a}, D=e^{2d}
//   score_l = const - 2*sum_h V_h/(1+A_lh*D_th)   -> const cancels in softmax
// R6 -> R7: k4 was VALU-issue-bound (92% VALUBusy), 1 wave64-rcp (8cy issue)
// per element. Now 4 fractions share ONE rcp via hierarchical merge:
//   v0/d0+v1/d1 = (v0 d1+v1 d0)/(d0 d1), twice -> rcp/4 elems.
// t's processed in f32x2 pairs so merges emit v_pk_fma_f32 (2x fp32 rate).
// A is stored as h-quads (uint2 = 4 bf16) for one 8B load per 4 h.
// k3: dot-chains split into 2 independent accumulators (latency hiding).
// ---------------------------------------------------------------------------

#define LOG2E  1.4426950408889634f
#define C2LOG2E 2.8853900817779268f   // 2*log2(e)

typedef float f32x2 __attribute__((ext_vector_type(2)));

__device__ __forceinline__ unsigned f2bf(float f) {
  unsigned u = __builtin_bit_cast(unsigned, f);
  return (u + 0x7fffu + ((u >> 16) & 1u)) >> 16;   // round-to-nearest-even
}
// bf16 bits in the LOW half of `bits` -> float. (High half ignored.)
__device__ __forceinline__ float bfbits2f(unsigned bits) {
  return __builtin_bit_cast(float, bits << 16);
}
// bf16 bits in the HIGH half of `bits` -> float (no shift needed).
__device__ __forceinline__ float bfhi2f(unsigned bits) {
  return __builtin_bit_cast(float, bits & 0xffff0000u);
}

#if defined(__has_builtin)
#  if __has_builtin(__builtin_amdgcn_fdot2_f32_bf16)
#    define HAS_DOT2_BF16 1
#  endif
#endif

#if defined(HAS_DOT2_BF16)
typedef __bf16 bf16x2v __attribute__((ext_vector_type(2)));
__device__ __forceinline__ float dot2bf(unsigned w, unsigned h, float acc) {
  return __builtin_amdgcn_fdot2_f32_bf16(__builtin_bit_cast(bf16x2v, w),
                                         __builtin_bit_cast(bf16x2v, h), acc, false);
}
#else
__device__ __forceinline__ float dot2bf(unsigned w, unsigned h, float acc) {
  float wl = __builtin_bit_cast(float, w << 16);
  float wh = __builtin_bit_cast(float, w & 0xffff0000u);
  float hl = __builtin_bit_cast(float, h << 16);
  float hh = __builtin_bit_cast(float, h & 0xffff0000u);
  return fmaf(wh, hh, fmaf(wl, hl, acc));
}
#endif

#if defined(__has_builtin) && __has_builtin(__builtin_amdgcn_rcpf)
#  define FAST_RCP(x) __builtin_amdgcn_rcpf(x)
#else
#  define FAST_RCP(x) (1.0f / (x))
#endif

__device__ __forceinline__ float fast_sigmoid(float x) {
  return FAST_RCP(1.f + exp2f(-LOG2E * x));
}
__device__ __forceinline__ float fast_tanh(float x) {
  return 1.f - 2.f * FAST_RCP(1.f + exp2f(C2LOG2E * x));
}

// --- k1: w1e = x@W1 + b1 ; store ATq[(b*64+hq)*1024 + l] = uint2 of 4 bf16
//     A[l, 4hq..4hq+3] where A = exp2(C2*w1e).  (h-quad layout for k4)
__global__ __launch_bounds__(256) void k1_w1e(const float* __restrict__ x,
                                              const float* __restrict__ W1,
                                              const float* __restrict__ b1,
                                              uint2* __restrict__ ATq) {
  __shared__ unsigned short tile[256 * 16];   // [h][lloc], 8 KiB
  const int b  = blockIdx.x >> 6;
  const int lb = blockIdx.x & 63;   // 16 l-rows per block
  const int h  = threadIdx.x;
  float acc[16];
  const float bias = b1[h];
#pragma unroll
  for (int r = 0; r < 16; ++r) acc[r] = bias;
  const float* xb = x + ((size_t)(b * 1024 + lb * 16)) * 256;
  for (int d0 = 0; d0 < 256; d0 += 4) {
    const float w0 = W1[(d0 + 0) * 256 + h];
    const float w1 = W1[(d0 + 1) * 256 + h];
    const float w2 = W1[(d0 + 2) * 256 + h];
    const float w3 = W1[(d0 + 3) * 256 + h];
#pragma unroll
    for (int r = 0; r < 16; ++r) {
      const float4 xv = *(const float4*)(xb + r * 256 + d0);
      acc[r] = fmaf(xv.x, w0, acc[r]);
      acc[r] = fmaf(xv.y, w1, acc[r]);
      acc[r] = fmaf(xv.z, w2, acc[r]);
      acc[r] = fmaf(xv.w, w3, acc[r]);
    }
  }
#pragma unroll
  for (int r = 0; r < 16; ++r)
    tile[h * 16 + r] = (unsigned short)f2bf(exp2f(C2LOG2E * acc[r]));
  __syncthreads();
  // write phase: 1024 uint2 outputs (hq, lloc), 4 per thread, coalesced.
#pragma unroll
  for (int k = 0; k < 4; ++k) {
    const int o = k * 256 + threadIdx.x;
    const int hq = o >> 4, lloc = o & 15;
    const unsigned s0 = tile[(4 * hq + 0) * 16 + lloc];
    const unsigned s1 = tile[(4 * hq + 1) * 16 + lloc];
    const unsigned s2 = tile[(4 * hq + 2) * 16 + lloc];
    const unsigned s3 = tile[(4 * hq + 3) * 16 + lloc];
    uint2 val;
    val.x = s0 | (s1 << 16);
    val.y = s2 | (s3 << 16);
    ATq[(((size_t)(b * 64 + hq)) << 10) + lb * 16 + lloc] = val;
  }
}

// --- k2: xz[b][j] = x[b][1023][:] @ Wk[:,j] + b[j]
__global__ __launch_bounds__(256) void k2_xz(const float* __restrict__ x,
                                             const float* __restrict__ Wk,
                                             const float* __restrict__ bvec,
                                             float* __restrict__ xz) {
  const int b = blockIdx.x, tid = threadIdx.x;
  float acc[4] = {bvec[tid], bvec[256 + tid], bvec[512 + tid], bvec[768 + tid]};
  const float* xr = x + ((size_t)b * 1024 + 1023) * 256;
  for (int d0 = 0; d0 < 256; d0 += 4) {
    const float4 xv = *(const float4*)(xr + d0);
#pragma unroll
    for (int i = 0; i < 4; ++i) {
      const float xs = (i == 0) ? xv.x : (i == 1) ? xv.y : (i == 2) ? xv.z : xv.w;
#pragma unroll
      for (int q = 0; q < 4; ++q)
        acc[q] = fmaf(xs, Wk[(size_t)(d0 + i) * 1024 + q * 256 + tid], acc[q]);
    }
  }
#pragma unroll
  for (int q = 0; q < 4; ++q) xz[b * 1024 + q * 256 + tid] = acc[q];
}

// --- k3: sequential LSTM recurrence. ONE WG (512 threads, 2 waves/EU) per batch.
// Thread owns columns (tid, tid+512). Weight bf16x2 row-pairs:
//   pairs 0..95   in VGPRs (96 x 2 cols = 192 regs)
//   pairs 96..127 in LDS   (32 pairs x 1024 cols x 4B = 128 KiB)
// 2 independent accumulator chains per column (latency hiding at 2 waves/EU).
__global__ __launch_bounds__(512, 2) void k3_recur(const float* __restrict__ xz,
                                                   const float* __restrict__ Wr,
                                                   unsigned short* __restrict__ hseq) {
  __shared__ __align__(16) unsigned Wtail[8 * 1024 * 4];  // 128 KiB, pairs 96..127
  __shared__ float z_lds[512];                            // zf, zo exchange
  __shared__ __align__(16) unsigned h_pk[128];            // h as bf16x2
  const int b   = blockIdx.x;
  const int tid = threadIdx.x;
  const int colA = tid, colB = tid + 512;

  unsigned wA[96], wB[96];
#pragma unroll
  for (int p = 0; p < 96; ++p) {
    wA[p] = f2bf(Wr[(size_t)(2 * p) * 1024 + colA]) |
            (f2bf(Wr[(size_t)(2 * p + 1) * 1024 + colA]) << 16);
    wB[p] = f2bf(Wr[(size_t)(2 * p) * 1024 + colB]) |
            (f2bf(Wr[(size_t)(2 * p + 1) * 1024 + colB]) << 16);
  }
#pragma unroll
  for (int gg = 0; gg < 8; ++gg) {
#pragma unroll
    for (int d = 0; d < 4; ++d) {
      const int p = 96 + gg * 4 + d;
      Wtail[(gg * 1024 + colA) * 4 + d] =
          f2bf(Wr[(size_t)(2 * p) * 1024 + colA]) |
          (f2bf(Wr[(size_t)(2 * p + 1) * 1024 + colA]) << 16);
      Wtail[(gg * 1024 + colB) * 4 + d] =
          f2bf(Wr[(size_t)(2 * p) * 1024 + colB]) |
          (f2bf(Wr[(size_t)(2 * p + 1) * 1024 + colB]) << 16);
    }
  }
  if (tid < 128) h_pk[tid] = 0u;
  const float zaA = xz[b * 1024 + colA];
  const float zaB = xz[b * 1024 + colB];
  float c = 0.f;
  __syncthreads();

  for (int t = 0; t < 1024; ++t) {
    float aA0 = zaA, aA1 = 0.f, aB0 = zaB, aB1 = 0.f;
#pragma unroll
    for (int g = 0; g < 12; ++g) {
      const uint4 hp = *(const uint4*)&h_pk[4 * g];
      aA0 = dot2bf(wA[4 * g + 0], hp.x, aA0);
      aA0 = dot2bf(wA[4 * g + 1], hp.y, aA0);
      aA0 = dot2bf(wA[4 * g + 2], hp.z, aA0);
      aA0 = dot2bf(wA[4 * g + 3], hp.w, aA0);
      aB0 = dot2bf(wB[4 * g + 0], hp.x, aB0);
      aB0 = dot2bf(wB[4 * g + 1], hp.y, aB0);
      aB0 = dot2bf(wB[4 * g + 2], hp.z, aB0);
      aB0 = dot2bf(wB[4 * g + 3], hp.w, aB0);
    }
#pragma unroll
    for (int g = 12; g < 24; ++g) {
      const uint4 hp = *(const uint4*)&h_pk[4 * g];
      aA1 = dot2bf(wA[4 * g + 0], hp.x, aA1);
      aA1 = dot2bf(wA[4 * g + 1], hp.y, aA1);
      aA1 = dot2bf(wA[4 * g + 2], hp.z, aA1);
      aA1 = dot2bf(wA[4 * g + 3], hp.w, aA1);
      aB1 = dot2bf(wB[4 * g + 0], hp.x, aB1);
      aB1 = dot2bf(wB[4 * g + 1], hp.y, aB1);
      aB1 = dot2bf(wB[4 * g + 2], hp.z, aB1);
      aB1 = dot2bf(wB[4 * g + 3], hp.w, aB1);
    }
#pragma unroll
    for (int gg = 0; gg < 8; ++gg) {
      const uint4 hp = *(const uint4*)&h_pk[96 + 4 * gg];
      const uint4 wa = *(const uint4*)&Wtail[(gg * 1024 + colA) * 4];
      const uint4 wb = *(const uint4*)&Wtail[(gg * 1024 + colB) * 4];
      float& rA = (gg < 4) ? aA0 : aA1;
      float& rB = (gg < 4) ? aB0 : aB1;
      rA = dot2bf(wa.x, hp.x, rA);
      rA = dot2bf(wa.y, hp.y, rA);
      rA = dot2bf(wa.z, hp.z, rA);
      rA = dot2bf(wa.w, hp.w, rA);
      rB = dot2bf(wb.x, hp.x, rB);
      rB = dot2bf(wb.y, hp.y, rB);
      rB = dot2bf(wb.z, hp.z, rB);
      rB = dot2bf(wb.w, hp.w, rB);
    }
    const float aA = aA0 + aA1;
    const float aB = aB0 + aB1;
    // z export: thread>=256 holds zf (colA in [256,512)) and zo (colB in [768,1024))
    if (tid >= 256) {
      z_lds[tid - 256] = aA;        // zf for h-elem (tid-256)
      z_lds[tid]       = aB;        // zo for h-elem (tid-256), offset +256
    }
    __syncthreads();
    // gates: thread<256 owns h-elem tid; zi = own colA, zg = own colB.
    if (tid < 256) {
      const float zi = aA;
      const float zg = aB;
      const float zf = z_lds[tid];
      const float zo = z_lds[tid + 256];
      const float ig = fast_sigmoid(zi);
      const float fg = fast_sigmoid(zf);
      const float gv = fast_tanh(zg);
      const float og = fast_sigmoid(zo);
      c = fmaf(fg, c, ig * gv);
      const float h = og * fast_tanh(c);
      const unsigned short hb = (unsigned short)f2bf(h);
      ((unsigned short*)h_pk)[tid] = hb;
      hseq[(size_t)(t * 64 + b) * 256 + tid] = hb;
    }
    __syncthreads();
  }
}

// --- k3b: w2d = hseq @ W2 + b2 for all (t,b); store D[b][t][h] = f32(exp2(C2*w2d))
__global__ __launch_bounds__(256) void k3b_w2d(const unsigned int* __restrict__ hseq,
                                               const float* __restrict__ W2,
                                               const float* __restrict__ b2,
                                               float* __restrict__ D) {
  const int r0 = blockIdx.x * 16;   // rows (t*64+b); 16 rows share one t
  const int h = threadIdx.x;
  float acc[16];
  const float bias = b2[h];
#pragma unroll
  for (int r = 0; r < 16; ++r) acc[r] = bias;
  for (int m0 = 0; m0 < 128; m0 += 2) {   // 2 dwords = 4 k values
    const float w0 = W2[(size_t)(2 * m0 + 0) * 256 + h];
    const float w1 = W2[(size_t)(2 * m0 + 1) * 256 + h];
    const float w2 = W2[(size_t)(2 * m0 + 2) * 256 + h];
    const float w3 = W2[(size_t)(2 * m0 + 3) * 256 + h];
#pragma unroll
    for (int r = 0; r < 16; ++r) {
      const uint2 hp = *(const uint2*)&hseq[(size_t)(r0 + r) * 128 + m0];
      acc[r] = fmaf(bfbits2f(hp.x),       w0, acc[r]);
      acc[r] = fmaf(bfbits2f(hp.x >> 16), w1, acc[r]);
      acc[r] = fmaf(bfbits2f(hp.y),       w2, acc[r]);
      acc[r] = fmaf(bfbits2f(hp.y >> 16), w3, acc[r]);
    }
  }
  const int t = r0 >> 6;
  const int bb0 = r0 & 63;
#pragma unroll
  for (int r = 0; r < 16; ++r) {
    D[((size_t)(bb0 + r) * 1024 + t) * 256 + h] = exp2f(C2LOG2E * acc[r]);
  }
}

// --- k4: attention scores + softmax.
// Block = (b, 16 t's). Wave handles 4 t's as two f32x2-paired t's; lane = l
// within 64-chunk, 16 chunks. 4 h's (one quad) share ONE rcp via fraction
// merging; t-pairs packed in f32x2 for v_pk_fma_f32.
__global__ __launch_bounds__(256, 3) void k4_attn(const uint2* __restrict__ ATq,
                                                  const float* __restrict__ Dm,
                                                  const float* __restrict__ V,
                                                  float* __restrict__ out) {
  const int b  = blockIdx.x >> 6;
  const int tb = blockIdx.x & 63;
  const int wv = threadIdx.x >> 6;
  const int lane = threadIdx.x & 63;
  const int t0 = tb * 16 + wv * 4;
  const uint2* Ab = ATq + (((size_t)b) << 16);           // b*64*1024
  const float* Db = Dm + ((size_t)(b * 1024) + t0) * 256;
  f32x2 acc2[2][16];   // [t-pair][lb]; .x = t0+2p, .y = t0+2p+1
#pragma unroll
  for (int p = 0; p < 2; ++p)
#pragma unroll
    for (int lb = 0; lb < 16; ++lb) acc2[p][lb] = (f32x2){0.f, 0.f};

  for (int hq = 0; hq < 64; ++hq) {
    const float4 vq  = *(const float4*)(V + hq * 4);
    const float4 Dr0 = *(const float4*)(Db + 0 * 256 + hq * 4);
    const float4 Dr1 = *(const float4*)(Db + 1 * 256 + hq * 4);
    const float4 Dr2 = *(const float4*)(Db + 2 * 256 + hq * 4);
    const float4 Dr3 = *(const float4*)(Db + 3 * 256 + hq * 4);
    // Dp[p][i] = {D[t0+2p][4hq+i], D[t0+2p+1][4hq+i]}
    f32x2 Dp[2][4];
    Dp[0][0] = (f32x2){Dr0.x, Dr1.x}; Dp[0][1] = (f32x2){Dr0.y, Dr1.y};
    Dp[0][2] = (f32x2){Dr0.z, Dr1.z}; Dp[0][3] = (f32x2){Dr0.w, Dr1.w};
    Dp[1][0] = (f32x2){Dr2.x, Dr3.x}; Dp[1][1] = (f32x2){Dr2.y, Dr3.y};
    Dp[1][2] = (f32x2){Dr2.z, Dr3.z}; Dp[1][3] = (f32x2){Dr2.w, Dr3.w};
    const f32x2 v0 = (f32x2){vq.x, vq.x};
    const f32x2 v1 = (f32x2){vq.y, vq.y};
    const f32x2 v2 = (f32x2){vq.z, vq.z};
    const f32x2 v3 = (f32x2){vq.w, vq.w};
    const uint2* Ah = Ab + ((size_t)hq << 10) + lane;
#pragma unroll
    for (int lb = 0; lb < 16; ++lb) {
      const uint2 aq = Ah[lb * 64];
      const f32x2 a0 = (f32x2){bfbits2f(aq.x), bfbits2f(aq.x)};
      const f32x2 a1 = (f32x2){bfhi2f(aq.x),   bfhi2f(aq.x)};
      const f32x2 a2 = (f32x2){bfbits2f(aq.y), bfbits2f(aq.y)};
      const f32x2 a3 = (f32x2){bfhi2f(aq.y),   bfhi2f(aq.y)};
      const f32x2 one = (f32x2){1.f, 1.f};
#pragma unroll
      for (int p = 0; p < 2; ++p) {
        const f32x2 d0 = a0 * Dp[p][0] + one;
        const f32x2 d1 = a1 * Dp[p][1] + one;
        const f32x2 d2 = a2 * Dp[p][2] + one;
        const f32x2 d3 = a3 * Dp[p][3] + one;
        const f32x2 n01 = v0 * d1 + v1 * d0;
        const f32x2 n23 = v2 * d3 + v3 * d2;
        const f32x2 d01 = d0 * d1;
        const f32x2 d23 = d2 * d3;
        const f32x2 nf = n01 * d23 + n23 * d01;
        const f32x2 df = d01 * d23;
        const f32x2 r = (f32x2){FAST_RCP(df.x), FAST_RCP(df.y)};
        acc2[p][lb] += nf * r;
      }
    }
  }
  // softmax over l (score = -2*acc; global constants cancel)
#pragma unroll
  for (int p = 0; p < 2; ++p)
#pragma unroll
    for (int half = 0; half < 2; ++half) {
      const int tt = 2 * p + half;
      float s[16];
      float m = -1e30f;
#pragma unroll
      for (int lb = 0; lb < 16; ++lb) {
        s[lb] = -2.f * (half ? acc2[p][lb].y : acc2[p][lb].x);
        m = fmaxf(m, s[lb]);
      }
      for (int off = 32; off > 0; off >>= 1) m = fmaxf(m, __shfl_xor(m, off, 64));
      float pr[16];
      float sum = 0.f;
#pragma unroll
      for (int lb = 0; lb < 16; ++lb) {
        pr[lb] = exp2f((s[lb] - m) * LOG2E);
        sum += pr[lb];
      }
      for (int off = 32; off > 0; off >>= 1) sum += __shfl_xor(sum, off, 64);
      const float rs = 1.f / sum;
      float* op = out + ((size_t)(b * 1024) + (t0 + tt)) * 1024 + lane;
#pragma unroll
      for (int lb = 0; lb < 16; ++lb) op[lb * 64] = pr[lb] * rs;
    }
}

// ---------------------------------------------------------------------------
extern "C" void kernel_launch(void* const* d_in, const int* in_sizes, int n_in,
                              void* d_out, int out_size, void* d_ws, size_t ws_size,
                              hipStream_t stream) {
  (void)in_sizes; (void)n_in; (void)out_size; (void)ws_size;
  const float* x  = (const float*)d_in[0];
  const float* Wk = (const float*)d_in[1];
  const float* Wr = (const float*)d_in[2];
  const float* bb = (const float*)d_in[3];
  const float* W1 = (const float*)d_in[4];
  const float* b1 = (const float*)d_in[5];
  const float* W2 = (const float*)d_in[6];
  const float* b2 = (const float*)d_in[7];
  const float* V  = (const float*)d_in[8];
  // d_in[9] = bV : constant over l, cancels in softmax.

  char* ws = (char*)d_ws;
  float*          Dm   = (float*)(ws);                          // 64 MiB f32 D[b][t][h]
  uint2*          ATq  = (uint2*)(ws + 67108864);               // 32 MiB bf16 A h-quads
  unsigned short* hseq = (unsigned short*)(ws + 100663296);     // 32 MiB bf16 h_t
  float*          xz   = (float*)(ws + 134217728);              // 256 KiB
  float* out = (float*)d_out;

  hipLaunchKernelGGL(k1_w1e, dim3(4096), dim3(256), 0, stream, x, W1, b1, ATq);
  hipLaunchKernelGGL(k2_xz, dim3(64), dim3(256), 0, stream, x, Wk, bb, xz);
  hipLaunchKernelGGL(k3_recur, dim3(64), dim3(512), 0, stream, xz, Wr, hseq);
  hipLaunchKernelGGL(k3b_w2d, dim3(4096), dim3(256), 0, stream, (const unsigned int*)hseq, W2, b2, Dm);
  hipLaunchKernelGGL(k4_attn, dim3(4096), dim3(256), 0, stream, ATq, Dm, V, out);
}